// Round 11
// baseline (1036.689 us; speedup 1.0000x reference)
//
#include <hip/hip_runtime.h>

#define W_OUT 12
#define N_CAPS 288
#define CIN 8
#define DD 16
#define A_DIM 32
#define B_DIM 4
#define CI 32
#define H_IN 14
#define NT 18            // n-rows per lane (288 / 16)
#define XSTRIDE 12       // x row stride (floats): 48B, 16B-aligned rows
#define NROWS2 768       // 32 ci * 4 ik * 6 jj  (covers i0..i0+1 sites)

__device__ __forceinline__ float4 shfl_xor4(float4 v, int m) {
    float4 r;
    r.x = __shfl_xor(v.x, m);
    r.y = __shfl_xor(v.y, m);
    r.z = __shfl_xor(v.z, m);
    r.w = __shfl_xor(v.w, m);
    return r;
}

__global__ __launch_bounds__(256, 2) void capsule_kernel(
    const float* __restrict__ x,
    const float* __restrict__ Wt,
    const float* __restrict__ bias,
    float* __restrict__ out)
{
    __shared__ __align__(16) float xs[NROWS2 * XSTRIDE];  // 36864 B
    __shared__ int xoff[N_CAPS];                          // 1152 B

    const int tid = threadIdx.x;
    int bid = blockIdx.x;
    const int jb = bid % 3; bid /= 3;
    const int ib = bid % 6; bid /= 6;
    const int b  = bid % B_DIM; bid /= B_DIM;
    const int a  = bid;
    const int i0 = ib * 2;
    const int j0 = jb * 4;

    // xoff[n] = LDS float offset of row n (ki,kj at irel=0, jj=kj)
    for (int n = tid; n < N_CAPS; n += 256) {
        int ci = n / 9, r = n % 9;
        xoff[n] = (ci * 24 + (r / 3) * 6 + (r % 3)) * XSTRIDE;
    }

    // stage x: rows (ci, ik=0..3, jj=0..5) covering sites (i0..i0+1) x (j0..j0+3)
    for (int row = tid; row < NROWS2; row += 256) {
        int ci = row / 24, rr = row % 24;
        int ik = rr / 6, jj = rr % 6;
        const float* src = x + ((((size_t)b * CI + ci) * H_IN + (i0 + ik)) * H_IN + (j0 + jj)) * CIN;
        float4 v0 = *reinterpret_cast<const float4*>(src);
        float4 v1 = *reinterpret_cast<const float4*>(src + 4);
        float* dst = &xs[row * XSTRIDE];
        *reinterpret_cast<float4*>(dst)     = v0;
        *reinterpret_cast<float4*>(dst + 4) = v1;
    }
    __syncthreads();
    // ---- no barriers below: each wave owns 2 sites (i0,j) & (i0+1,j) ----

    const int lane = tid & 63;
    const int wv   = tid >> 6;          // wave id = j - j0
    const int dq   = lane & 3;          // d-quad
    const int nr   = lane >> 2;         // n residue

    const float* Wa = Wt + (size_t)a * (N_CAPS * CIN * DD);
    const int base0 = wv * XSTRIDE;     // site0 x offset; site1 = +72 (one ik row block)

    // ---- priors for BOTH sites from one W stream (R11): halves L2 W-traffic
    // (R9 measured 28 TB/s ~ 81% of L2 ceiling => BW-bound). Ping-pong W
    // prefetch + sched_barrier(0) fences per R8/R9 (bounded hoisting).
    float4 ps0[NT], ps1[NT];
    float4 wA[CIN], wB[CIN];
    {
        const float* wp = Wa + (size_t)nr * (CIN * DD) + dq * 4;
        #pragma unroll
        for (int c = 0; c < CIN; ++c) wA[c] = *reinterpret_cast<const float4*>(wp + c * DD);
    }
    #pragma unroll
    for (int tt = 0; tt < NT; tt += 2) {
        {   // prefetch t = tt+1
            const float* wp = Wa + (size_t)(nr + 16 * (tt + 1)) * (CIN * DD) + dq * 4;
            #pragma unroll
            for (int c = 0; c < CIN; ++c) wB[c] = *reinterpret_cast<const float4*>(wp + c * DD);
        }
        {   // compute t = tt from wA
            const float* xp = &xs[xoff[nr + 16 * tt] + base0];
            float xr0[CIN], xr1[CIN];
            *reinterpret_cast<float4*>(&xr0[0]) = *reinterpret_cast<const float4*>(xp);
            *reinterpret_cast<float4*>(&xr0[4]) = *reinterpret_cast<const float4*>(xp + 4);
            *reinterpret_cast<float4*>(&xr1[0]) = *reinterpret_cast<const float4*>(xp + 72);
            *reinterpret_cast<float4*>(&xr1[4]) = *reinterpret_cast<const float4*>(xp + 76);
            float4 a0 = {0.f,0.f,0.f,0.f}, a1 = {0.f,0.f,0.f,0.f};
            #pragma unroll
            for (int c = 0; c < CIN; ++c) {
                float4 w4 = wA[c];
                a0.x = fmaf(xr0[c], w4.x, a0.x); a0.y = fmaf(xr0[c], w4.y, a0.y);
                a0.z = fmaf(xr0[c], w4.z, a0.z); a0.w = fmaf(xr0[c], w4.w, a0.w);
                a1.x = fmaf(xr1[c], w4.x, a1.x); a1.y = fmaf(xr1[c], w4.y, a1.y);
                a1.z = fmaf(xr1[c], w4.z, a1.z); a1.w = fmaf(xr1[c], w4.w, a1.w);
            }
            ps0[tt] = a0; ps1[tt] = a1;
        }
        __builtin_amdgcn_sched_barrier(0);
        if (tt + 2 < NT) {   // prefetch t = tt+2
            const float* wp = Wa + (size_t)(nr + 16 * (tt + 2)) * (CIN * DD) + dq * 4;
            #pragma unroll
            for (int c = 0; c < CIN; ++c) wA[c] = *reinterpret_cast<const float4*>(wp + c * DD);
        }
        {   // compute t = tt+1 from wB
            const float* xp = &xs[xoff[nr + 16 * (tt + 1)] + base0];
            float xr0[CIN], xr1[CIN];
            *reinterpret_cast<float4*>(&xr0[0]) = *reinterpret_cast<const float4*>(xp);
            *reinterpret_cast<float4*>(&xr0[4]) = *reinterpret_cast<const float4*>(xp + 4);
            *reinterpret_cast<float4*>(&xr1[0]) = *reinterpret_cast<const float4*>(xp + 72);
            *reinterpret_cast<float4*>(&xr1[4]) = *reinterpret_cast<const float4*>(xp + 76);
            float4 a0 = {0.f,0.f,0.f,0.f}, a1 = {0.f,0.f,0.f,0.f};
            #pragma unroll
            for (int c = 0; c < CIN; ++c) {
                float4 w4 = wB[c];
                a0.x = fmaf(xr0[c], w4.x, a0.x); a0.y = fmaf(xr0[c], w4.y, a0.y);
                a0.z = fmaf(xr0[c], w4.z, a0.z); a0.w = fmaf(xr0[c], w4.w, a0.w);
                a1.x = fmaf(xr1[c], w4.x, a1.x); a1.y = fmaf(xr1[c], w4.y, a1.y);
                a1.z = fmaf(xr1[c], w4.z, a1.z); a1.w = fmaf(xr1[c], w4.w, a1.w);
            }
            ps0[tt + 1] = a0; ps1[tt + 1] = a1;
        }
        __builtin_amdgcn_sched_barrier(0);
    }

    const float4 bv = *reinterpret_cast<const float4*>(bias + a * DD + dq * 4);

    // ---- routing + store for one site (inlined twice; sequential keeps
    // register peak low: ps0 dies before site1's lt peaks). No e[] array —
    // exp recomputed — to stay under the 256-VGPR budget.
    auto route_store = [&](float4 (&ps)[NT], int irow) {
        float lt[NT];
        float4 out4;
        {   // iter 0: probs = 1/288
            float4 s = {0.f,0.f,0.f,0.f};
            #pragma unroll
            for (int t = 0; t < NT; ++t) {
                s.x += ps[t].x; s.y += ps[t].y; s.z += ps[t].z; s.w += ps[t].w;
            }
            #pragma unroll
            for (int m = 4; m <= 32; m <<= 1) { float4 o = shfl_xor4(s, m); s.x += o.x; s.y += o.y; s.z += o.z; s.w += o.w; }
            const float inv0 = 1.0f / 288.0f;
            s.x = fmaf(s.x, inv0, bv.x); s.y = fmaf(s.y, inv0, bv.y);
            s.z = fmaf(s.z, inv0, bv.z); s.w = fmaf(s.w, inv0, bv.w);
            float sn = s.x*s.x + s.y*s.y + s.z*s.z + s.w*s.w;
            sn += __shfl_xor(sn, 1); sn += __shfl_xor(sn, 2);
            float factor = sn / (1.0f + sn) * rsqrtf(sn);
            out4.x = factor * s.x; out4.y = factor * s.y; out4.z = factor * s.z; out4.w = factor * s.w;
            #pragma unroll
            for (int t = 0; t < NT; ++t) {
                float p = ps[t].x*out4.x + ps[t].y*out4.y + ps[t].z*out4.z + ps[t].w*out4.w;
                p += __shfl_xor(p, 1);
                p += __shfl_xor(p, 2);
                lt[t] = p;
            }
        }
        #pragma unroll
        for (int it = 1; it < 3; ++it) {
            // lt replicated across dq lanes -> reduce over nr bits ONLY (masks 4..32)
            float m = -1e30f;
            #pragma unroll
            for (int t = 0; t < NT; ++t) m = fmaxf(m, lt[t]);
            #pragma unroll
            for (int msk = 4; msk <= 32; msk <<= 1) m = fmaxf(m, __shfl_xor(m, msk));
            float se = 0.f;
            #pragma unroll
            for (int t = 0; t < NT; ++t) se += __expf(lt[t] - m);
            #pragma unroll
            for (int msk = 4; msk <= 32; msk <<= 1) se += __shfl_xor(se, msk);
            const float inv = 1.0f / se;

            float4 s = {0.f,0.f,0.f,0.f};
            #pragma unroll
            for (int t = 0; t < NT; ++t) {
                float e = __expf(lt[t] - m);
                s.x = fmaf(e, ps[t].x, s.x); s.y = fmaf(e, ps[t].y, s.y);
                s.z = fmaf(e, ps[t].z, s.z); s.w = fmaf(e, ps[t].w, s.w);
            }
            #pragma unroll
            for (int msk = 4; msk <= 32; msk <<= 1) { float4 o = shfl_xor4(s, msk); s.x += o.x; s.y += o.y; s.z += o.z; s.w += o.w; }
            s.x = fmaf(s.x, inv, bv.x); s.y = fmaf(s.y, inv, bv.y);
            s.z = fmaf(s.z, inv, bv.z); s.w = fmaf(s.w, inv, bv.w);

            float sn = s.x*s.x + s.y*s.y + s.z*s.z + s.w*s.w;
            sn += __shfl_xor(sn, 1); sn += __shfl_xor(sn, 2);
            float factor = sn / (1.0f + sn) * rsqrtf(sn);
            out4.x = factor * s.x; out4.y = factor * s.y; out4.z = factor * s.z; out4.w = factor * s.w;

            if (it != 2) {
                #pragma unroll
                for (int t = 0; t < NT; ++t) {
                    float p = ps[t].x*out4.x + ps[t].y*out4.y + ps[t].z*out4.z + ps[t].w*out4.w;
                    p += __shfl_xor(p, 1);
                    p += __shfl_xor(p, 2);
                    lt[t] += p;
                }
            }
        }
        if (nr == 0) {
            size_t o = ((((size_t)b * A_DIM + a) * W_OUT + irow) * W_OUT + (j0 + wv)) * DD + dq * 4;
            *reinterpret_cast<float4*>(out + o) = out4;
        }
    };

    route_store(ps0, i0);
    route_store(ps1, i0 + 1);
}

extern "C" void kernel_launch(void* const* d_in, const int* in_sizes, int n_in,
                              void* d_out, int out_size, void* d_ws, size_t ws_size,
                              hipStream_t stream) {
    const float* x    = (const float*)d_in[0];
    const float* Wt   = (const float*)d_in[1];
    const float* bias = (const float*)d_in[2];
    float* out = (float*)d_out;
    (void)in_sizes; (void)n_in; (void)out_size; (void)d_ws; (void)ws_size;

    const int grid = A_DIM * B_DIM * 6 * 3;   // 2304 blocks, 8 sites each
    capsule_kernel<<<grid, 256, 0, stream>>>(x, Wt, bias, out);
}

// Round 12
// 153.595 us; speedup vs baseline: 6.7495x; 6.7495x over previous
//
#include <hip/hip_runtime.h>

#define W_OUT 12
#define N_CAPS 288
#define CIN 8
#define DD 16
#define A_DIM 32
#define B_DIM 4
#define CI 32
#define H_IN 14
#define NT 18            // n-rows per lane (288 / 16)
#define XSTRIDE 12       // x row stride (floats): 48B, 16B-aligned rows
#define NROWS 576        // 32 ci * 3 ki * 6 jj
#define TS_F 2048        // floats per t-step of W (16 n-rows * 128)
#define CH 3             // t-steps per staged chunk (24 KB)
#define NSTG 6           // NT / CH chunks

__device__ __forceinline__ float4 shfl_xor4(float4 v, int m) {
    float4 r;
    r.x = __shfl_xor(v.x, m);
    r.y = __shfl_xor(v.y, m);
    r.z = __shfl_xor(v.z, m);
    r.w = __shfl_xor(v.w, m);
    return r;
}

__device__ __forceinline__ void stage_piece(const float* g, float* lds) {
    // async global->LDS DMA, 16B/lane; LDS dest = uniform base + lane*16 (linear)
    __builtin_amdgcn_global_load_lds(
        (const __attribute__((address_space(1))) void*)g,
        (__attribute__((address_space(3))) void*)lds, 16, 0, 0);
}

__global__ __launch_bounds__(256, 2) void capsule_kernel(
    const float* __restrict__ x,
    const float* __restrict__ Wt,
    const float* __restrict__ bias,
    float* __restrict__ out)
{
    __shared__ __align__(16) float xs[NROWS * XSTRIDE];   // 27648 B
    __shared__ __align__(16) float wbuf[2][CH * TS_F];    // 49152 B double buffer
    __shared__ int xoff[N_CAPS];                          // 1152 B

    const int tid = threadIdx.x;
    int bid = blockIdx.x;
    const int jb = bid % 3; bid /= 3;
    const int i  = bid % W_OUT; bid /= W_OUT;
    const int b  = bid % B_DIM; bid /= B_DIM;
    const int a  = bid;
    const int j0 = jb * 4;

    const int lane = tid & 63;
    const int wv   = tid >> 6;          // wave id = site j - j0
    const int dq   = lane & 3;          // d-quad
    const int nr   = lane >> 2;         // n residue

    const float* Wa = Wt + (size_t)a * (N_CAPS * CIN * DD);

    // ---- W staging, TRANSPOSED so reads are stride-1 (R12; R10's layout was
    // an 8-way conflict). LDS f4 slot L = c*64 + n_loc*4 + dq holds global f4
    // G = n_loc*32 + c*4 + dq. global_load_lds: lane l of piece p (=c) writes
    // slot p*64+l, so its SOURCE is G(l,p) = (l>>2)*32 + p*4 + (l&3).
    // Read side: lane (nr,dq) reads slot c*64 + lane -> perfectly linear.
    const int g0 = (lane >> 2) * 128 + (lane & 3) * 4;   // source float offset, + p*16
    auto issue_chunk = [&](int t0, int buf) {
        #pragma unroll
        for (int k = 0; k < CH; ++k) {
            const float* base = Wa + (size_t)(t0 + k) * TS_F;
            #pragma unroll
            for (int q = 0; q < 2; ++q) {
                const int p = wv * 2 + q;                // piece 0..7 = c index
                stage_piece(base + g0 + p * 16, &wbuf[buf][k * TS_F + p * 256]);
            }
        }
    };

    issue_chunk(0, 0);   // chunk 0 DMA overlaps x staging

    // xoff[n] = LDS float offset of row n's x data (site sj=0)
    for (int n = tid; n < N_CAPS; n += 256) {
        int ci = n / 9, r = n % 9;
        xoff[n] = (ci * 18 + (r / 3) * 6 + (r % 3)) * XSTRIDE;
    }
    // stage x window: rows (ci, ki, jj), jj = 0..5 covering sites j0..j0+3
    for (int row = tid; row < NROWS; row += 256) {
        int ci = row / 18, rr = row % 18;
        int ki = rr / 6, jj = rr % 6;
        const float* src = x + ((((size_t)b * CI + ci) * H_IN + (i + ki)) * H_IN + (j0 + jj)) * CIN;
        float4 v0 = *reinterpret_cast<const float4*>(src);
        float4 v1 = *reinterpret_cast<const float4*>(src + 4);
        float* dst = &xs[row * XSTRIDE];
        *reinterpret_cast<float4*>(dst)     = v0;
        *reinterpret_cast<float4*>(dst + 4) = v1;
    }
    const float4 bv = *reinterpret_cast<const float4*>(bias + a * DD + dq * 4);
    __syncthreads();          // drains vmcnt/lgkm: xs + chunk 0 ready
    issue_chunk(CH, 1);       // chunk 1 in flight during compute of chunk 0

    const int sjoff = wv * XSTRIDE;

    // ---- priors: ps[t] = prior[n = nr+16t][4dq..4dq+3], W from LDS.
    float4 ps[NT];
    #pragma unroll
    for (int s = 0; s < NSTG; ++s) {
        #pragma unroll
        for (int k = 0; k < CH; ++k) {
            const int t = s * CH + k;
            const int n = nr + 16 * t;
            const float* xp = &xs[xoff[n] + sjoff];
            float xr[CIN];
            *reinterpret_cast<float4*>(&xr[0]) = *reinterpret_cast<const float4*>(xp);
            *reinterpret_cast<float4*>(&xr[4]) = *reinterpret_cast<const float4*>(xp + 4);
            const float4* wb4 = reinterpret_cast<const float4*>(&wbuf[s & 1][k * TS_F]);
            float4 acc = {0.f, 0.f, 0.f, 0.f};
            #pragma unroll
            for (int c = 0; c < CIN; ++c) {
                float4 w4 = wb4[c * 64 + lane];
                acc.x = fmaf(xr[c], w4.x, acc.x);
                acc.y = fmaf(xr[c], w4.y, acc.y);
                acc.z = fmaf(xr[c], w4.z, acc.z);
                acc.w = fmaf(xr[c], w4.w, acc.w);
            }
            ps[t] = acc;
        }
        if (s < NSTG - 1) {
            asm volatile("s_waitcnt lgkmcnt(0)" ::: "memory");
            __builtin_amdgcn_s_barrier();                 // all waves done with buf[s&1]
            if (s + 2 < NSTG) {
                issue_chunk((s + 2) * CH, s & 1);         // refill freed buffer
                asm volatile("s_waitcnt vmcnt(6)" ::: "memory");   // chunk s+1 landed
            } else {
                asm volatile("s_waitcnt vmcnt(0)" ::: "memory");
            }
            __builtin_amdgcn_s_barrier();                 // chunk s+1 visible to all
            __builtin_amdgcn_sched_barrier(0);
        }
    }

    float lt[NT];     // logits for rows n = nr+16t (replicated across dq lanes)
    float4 out4;

    // ---------- iter 0: logits all zero -> probs = 1/288 ----------
    {
        float4 s = {0.f, 0.f, 0.f, 0.f};
        #pragma unroll
        for (int t = 0; t < NT; ++t) {
            s.x += ps[t].x; s.y += ps[t].y; s.z += ps[t].z; s.w += ps[t].w;
        }
        #pragma unroll
        for (int m = 4; m <= 32; m <<= 1) { float4 o = shfl_xor4(s, m); s.x += o.x; s.y += o.y; s.z += o.z; s.w += o.w; }
        const float inv0 = 1.0f / 288.0f;
        s.x = fmaf(s.x, inv0, bv.x); s.y = fmaf(s.y, inv0, bv.y);
        s.z = fmaf(s.z, inv0, bv.z); s.w = fmaf(s.w, inv0, bv.w);
        float sn = s.x*s.x + s.y*s.y + s.z*s.z + s.w*s.w;
        sn += __shfl_xor(sn, 1); sn += __shfl_xor(sn, 2);
        float factor = sn / (1.0f + sn) * rsqrtf(sn);
        out4.x = factor * s.x; out4.y = factor * s.y; out4.z = factor * s.z; out4.w = factor * s.w;

        #pragma unroll
        for (int t = 0; t < NT; ++t) {
            float p = ps[t].x*out4.x + ps[t].y*out4.y + ps[t].z*out4.z + ps[t].w*out4.w;
            p += __shfl_xor(p, 1);
            p += __shfl_xor(p, 2);
            lt[t] = p;
        }
    }

    // ---------- iters 1, 2 ----------
    #pragma unroll
    for (int it = 1; it < 3; ++it) {
        // lt is REPLICATED across the 4 dq lanes -> softmax reduces cross nr
        // bits ONLY (masks 4..32); masks 1,2 would count each residue 4x.
        float m = -1e30f;
        #pragma unroll
        for (int t = 0; t < NT; ++t) m = fmaxf(m, lt[t]);
        #pragma unroll
        for (int msk = 4; msk <= 32; msk <<= 1) m = fmaxf(m, __shfl_xor(m, msk));
        float e[NT];
        float se = 0.f;
        #pragma unroll
        for (int t = 0; t < NT; ++t) { e[t] = __expf(lt[t] - m); se += e[t]; }
        #pragma unroll
        for (int msk = 4; msk <= 32; msk <<= 1) se += __shfl_xor(se, msk);
        const float inv = 1.0f / se;

        float4 s = {0.f, 0.f, 0.f, 0.f};
        #pragma unroll
        for (int t = 0; t < NT; ++t) {
            s.x = fmaf(e[t], ps[t].x, s.x); s.y = fmaf(e[t], ps[t].y, s.y);
            s.z = fmaf(e[t], ps[t].z, s.z); s.w = fmaf(e[t], ps[t].w, s.w);
        }
        #pragma unroll
        for (int msk = 4; msk <= 32; msk <<= 1) { float4 o = shfl_xor4(s, msk); s.x += o.x; s.y += o.y; s.z += o.z; s.w += o.w; }
        s.x = fmaf(s.x, inv, bv.x); s.y = fmaf(s.y, inv, bv.y);
        s.z = fmaf(s.z, inv, bv.z); s.w = fmaf(s.w, inv, bv.w);

        float sn = s.x*s.x + s.y*s.y + s.z*s.z + s.w*s.w;
        sn += __shfl_xor(sn, 1); sn += __shfl_xor(sn, 2);
        float factor = sn / (1.0f + sn) * rsqrtf(sn);
        out4.x = factor * s.x; out4.y = factor * s.y; out4.z = factor * s.z; out4.w = factor * s.w;

        if (it != 2) {
            #pragma unroll
            for (int t = 0; t < NT; ++t) {
                float p = ps[t].x*out4.x + ps[t].y*out4.y + ps[t].z*out4.z + ps[t].w*out4.w;
                p += __shfl_xor(p, 1);
                p += __shfl_xor(p, 2);
                lt[t] += p;
            }
        }
    }

    // ---- store: out[b][a][i][j0+wv][d], 4 lanes (nr==0) x float4 each
    if (nr == 0) {
        size_t o = ((((size_t)b * A_DIM + a) * W_OUT + i) * W_OUT + (j0 + wv)) * DD + dq * 4;
        *reinterpret_cast<float4*>(out + o) = out4;
    }
}

extern "C" void kernel_launch(void* const* d_in, const int* in_sizes, int n_in,
                              void* d_out, int out_size, void* d_ws, size_t ws_size,
                              hipStream_t stream) {
    const float* x    = (const float*)d_in[0];
    const float* Wt   = (const float*)d_in[1];
    const float* bias = (const float*)d_in[2];
    float* out = (float*)d_out;
    (void)in_sizes; (void)n_in; (void)out_size; (void)d_ws; (void)ws_size;

    const int grid = A_DIM * B_DIM * W_OUT * 3;   // 4608 blocks, 4 sites each
    capsule_kernel<<<grid, 256, 0, stream>>>(x, Wt, bias, out);
}